// Round 11
// baseline (110.163 us; speedup 1.0000x reference)
//
#include <hip/hip_runtime.h>
#include <hip/hip_cooperative_groups.h>

namespace cg = cooperative_groups;

// Problem constants (fixed by setup_inputs)
#define BATCH 2
#define NPTS  8192
#define KS    16
#define KNN   8
#define R2LOOSE 0.0101f      // loose prefilter ball; exact radius test at end
#define KEYMASK 0xFFFFE000u  // high 19 bits of d2; low 13 bits = sorted pos
#define NCELL   1000         // 10x10x10 grid, cell size 0.1 (= RADIUS)
#define CSTRIDE 1024         // padded per-batch cell-array stride

// Fused kernel geometry: 256 blocks x 512 threads, 1 block/CU (cooperative)
#define QB       64                 // queries per block
#define NWAVE    8                  // waves per block (512 threads)
#define NTHREADS 512
#define CAP      32                 // collect capacity per thread
#define SLAB     256                // per-wave staged candidates per chunk
#define NBLK     (BATCH * NPTS / QB)   // 256 blocks

__device__ __forceinline__ int cell_of(float x, float y, float z) {
    int cx = (int)(x * 10.0f); cx = cx > 9 ? 9 : cx;
    int cy = (int)(y * 10.0f); cy = cy > 9 ? 9 : cy;
    int cz = (int)(z * 10.0f); cz = cz > 9 ? 9 : cz;
    return (cx * 10 + cy) * 10 + cz;
}

#define CEX(a, b) { const unsigned mn_ = min(a, b), mx_ = max(a, b); \
                    a = mn_; b = mx_; }

// ---- fused build + knn + loss (R11: one cooperative launch) ---------------
// Phase A (blocks 0..15): R0-class build at 512 threads (16 pts/thread;
// 8 segment-ordered atomic rounds, 2 adds/thread/round -> same segment-major
// + arbitrary-intra-segment rank semantics). Pair-cell scan (thread owns
// cells 2t, 2t+1). Phase B (all 256 blocks): R10 knn, unchanged.
__global__ __launch_bounds__(512) void fused_kernel(
    const float* __restrict__ pc,
    const float* __restrict__ mask,
    float4* __restrict__ cs, int* __restrict__ sidx,
    int* __restrict__ cstart, float* __restrict__ out)
{
    __shared__ float4   stg4[NWAVE][SLAB];     // 32 KB per-wave slabs
    __shared__ int      stgi[NWAVE][SLAB];     //  8 KB their sorted positions
    __shared__ unsigned sbuf[CAP * NTHREADS];  // 64 KB collect buffer
    __shared__ int      fidx[QB * KNN];        //  2 KB
    __shared__ int      qid[QB];
    __shared__ float    red[NWAVE];
    __shared__ int      h[1024];               //  4 KB build histogram
    __shared__ int      wsum[8];

    const int t = threadIdx.x;
    const int blk = blockIdx.x;
    const int lane = t & 63;
    const int w = t >> 6;

    // ================= Phase A: build (blocks 0..15) =================
    if (blk < 16) {
        const int bb = blk >> 3, seg = blk & 7;   // batch, own segment
        h[t] = 0; h[t + 512] = 0;
        if (blk == 0 && t == 0) out[0] = 0.0f;

        const float* p = pc + (size_t)bb * NPTS * 3;
        float X0[8], Y0[8], Z0[8], X1[8], Y1[8], Z1[8];
        int C0[8], C1[8];
#pragma unroll
        for (int j = 0; j < 8; ++j) {
            const int i0 = j * 1024 + t;
            const int i1 = i0 + 512;
            X0[j] = p[3 * i0]; Y0[j] = p[3 * i0 + 1]; Z0[j] = p[3 * i0 + 2];
            X1[j] = p[3 * i1]; Y1[j] = p[3 * i1 + 1]; Z1[j] = p[3 * i1 + 2];
            C0[j] = cell_of(X0[j], Y0[j], Z0[j]);
            C1[j] = cell_of(X1[j], Y1[j], Z1[j]);
        }
        __syncthreads();   // h zeroed

        int r0 = 0, r1 = 0;
#pragma unroll
        for (int j = 0; j < 8; ++j) {          // segment-ordered rounds
            const int o0 = atomicAdd(&h[C0[j]], 1);
            const int o1 = atomicAdd(&h[C1[j]], 1);
            if (j == seg) { r0 = o0; r1 = o1; }
            __syncthreads();
        }

        // pair-cell exclusive scan: thread t owns cells 2t, 2t+1
        const int c0 = h[2 * t], c1 = h[2 * t + 1];
        const int ps = c0 + c1;
        int inc = ps;
#pragma unroll
        for (int off = 1; off < 64; off <<= 1) {
            const int v = __shfl_up(inc, off);
            if (lane >= off) inc += v;
        }
        if (lane == 63) wsum[w] = inc;
        __syncthreads();
        if (w == 0) {
            const int v = (lane < 8) ? wsum[lane] : 0;
            int iv = v;
#pragma unroll
            for (int off = 1; off < 8; off <<= 1) {
                const int u = __shfl_up(iv, off);
                if (lane >= off) iv += u;
            }
            if (lane < 8) wsum[lane] = iv - v;  // exclusive wave offsets
        }
        __syncthreads();
        const int excl = inc - ps + wsum[w];    // start of cell 2t
        const int s0 = excl, s1 = excl + c0;
        if (seg == 0) {
            cstart[bb * CSTRIDE + 2 * t]     = s0;
            cstart[bb * CSTRIDE + 2 * t + 1] = s1;
        }
        __syncthreads();
        h[2 * t] = s0; h[2 * t + 1] = s1;       // per-cell starts
        __syncthreads();

        // select own-segment points (uniform seg -> cndmask chains)
        float ax = X0[0], ay = Y0[0], az = Z0[0]; int ac = C0[0];
        float bx = X1[0], by = Y1[0], bz = Z1[0]; int bc = C1[0];
#pragma unroll
        for (int j = 1; j < 8; ++j)
            if (seg == j) {
                ax = X0[j]; ay = Y0[j]; az = Z0[j]; ac = C0[j];
                bx = X1[j]; by = Y1[j]; bz = Z1[j]; bc = C1[j];
            }

        const int pos0 = h[ac] + r0;
        const int pos1 = h[bc] + r1;
        const float sqa = fmaf(az, az, fmaf(ay, ay, ax * ax));
        const float sqb = fmaf(bz, bz, fmaf(by, by, bx * bx));
        cs[bb * NPTS + pos0]   = make_float4(ax, ay, az, -0.5f * sqa);
        cs[bb * NPTS + pos1]   = make_float4(bx, by, bz, -0.5f * sqb);
        sidx[bb * NPTS + pos0] = seg * 1024 + t;
        sidx[bb * NPTS + pos1] = seg * 1024 + 512 + t;
        __threadfence();   // publish before grid-wide sync
    }

    cg::this_grid().sync();

    // ================= Phase B: knn + loss (all 256 blocks) =================
    const int l = t & 63;
    const int k = l & 7;          // candidate sublane 0..7
    const int s = t >> 6;         // wave id 0..7
    const int su = __builtin_amdgcn_readfirstlane(s);
    const int Q = (t >> 3) & 63;  // query slot 0..63
    const int b  = blk >> 7;
    const int q0 = (blk & 127) * QB;
    const int qpos = q0 + Q;

    const float4* csb = cs + b * NPTS;
    const float4 qc = csb[qpos];
    const int    qi = sidx[b * NPTS + qpos];
    if (k == 0) qid[Q] = qi;

    const float qx = qc.x, qy = qc.y, qz = qc.z;
    const float qs = -2.0f * qc.w;                 // exact (power of 2)
    const float negthr = (qs - R2LOOSE) * 0.5f;    // pass iff tt >= negthr
    const unsigned SENT = (__float_as_uint(R2LOOSE) & KEYMASK) | 0x1FFFu;

    // wave's 8-query lex-cell run
    int lex = cell_of(qx, qy, qz);
    int cmn = lex, cmx = lex;
#pragma unroll
    for (int off = 32; off; off >>= 1) {
        cmn = min(cmn, __shfl_xor(cmn, off));
        cmx = max(cmx, __shfl_xor(cmx, off));
    }
    const int cfirst = __builtin_amdgcn_readfirstlane(cmn);
    const int clast  = __builtin_amdgcn_readfirstlane(cmx);

    // 9 covering intervals: independent bound loads + value-space dedup
    const int* csp = cstart + b * CSTRIDE;
    const int offs[9] = {-110, -100, -90, -10, 0, 10, 90, 100, 110};
    int praw[9], eraw[9];
#pragma unroll
    for (int i = 0; i < 9; ++i) {
        int lo = cfirst + offs[i] - 1;
        int hp = clast + offs[i] + 2;            // exclusive
        lo = min(max(lo, 0), 1000);
        hp = min(max(hp, 0), 1000);
        praw[i] = csp[lo];
        eraw[i] = csp[hp];
    }
    int P[9], cum[9];
    int runv = 0, Cw = 0;                        // runv == csp[run]
#pragma unroll
    for (int i = 0; i < 9; ++i) {
        const int p = max(praw[i], runv);
        const int e = max(eraw[i], p);
        runv = e;
        P[i] = p; cum[i] = Cw; Cw += e - p;
    }

    // append-only collect, branchless
    int cnt = 0;
    auto EVAL = [&](const float4& c, int spos) {
        const float tt = fmaf(c.x, qx, fmaf(c.y, qy, fmaf(c.z, qz, c.w)));
        const float d2 = fmaxf(fmaf(-2.0f, tt, qs), 0.0f);
        const unsigned key =
            (__float_as_uint(d2) & KEYMASK) | (unsigned)spos;
        const int slot = cnt < (CAP - 1) ? cnt : (CAP - 1);
        sbuf[slot * NTHREADS + t] = key;
        cnt += (tt >= negthr) ? 1 : 0;
    };

    // chunked per-wave stage + eval (wave-local fences only)
    for (int fb = 0; fb < Cw; fb += SLAB) {
        const int n = min(SLAB, Cw - fb);        // wave-uniform
        for (int f = l; f < n; f += 64) {        // 64-wide coalesced stage
            const int g = fb + f;
            int sp = P[0] + g;
#pragma unroll
            for (int i = 1; i < 9; ++i)
                sp = (g >= cum[i]) ? P[i] + (g - cum[i]) : sp;
            stg4[su][f] = csb[sp];
            stgi[su][f] = sp;
        }
        asm volatile("s_waitcnt lgkmcnt(0)" ::: "memory");  // stage visible

        for (int j = k; j < n; j += 8) {         // sublane-strided eval
            const float4 c = stg4[su][j];
            const int   sp = stgi[su][j];
            EVAL(c, sp);
        }
        asm volatile("s_waitcnt lgkmcnt(0)" ::: "memory");  // reads done
    }

    // per-thread ascending top-8 of own collected keys
    unsigned md[KNN];
#pragma unroll
    for (int kk = 0; kk < KNN; ++kk) md[kk] = SENT;
    const int m = cnt < CAP ? cnt : CAP;
    for (int kk = 0; kk < m; ++kk) {
        unsigned ky = sbuf[kk * NTHREADS + t];
#pragma unroll
        for (int i = 0; i < KNN; ++i) {
            const unsigned mn = min(ky, md[i]);
            const unsigned mx = max(ky, md[i]);
            md[i] = mn; ky = mx;
        }
    }

    // in-register bitonic merge across the 8 sublanes of each query group
#pragma unroll
    for (int off = 1; off <= 4; off <<= 1) {
        unsigned bb2[8], cc[8];
#pragma unroll
        for (int j = 0; j < 8; ++j)
            bb2[j] = (unsigned)__shfl_xor((int)md[j], off);
#pragma unroll
        for (int j = 0; j < 8; ++j)
            cc[j] = min(md[j], bb2[7 - j]);
        CEX(cc[0], cc[4]); CEX(cc[1], cc[5]);
        CEX(cc[2], cc[6]); CEX(cc[3], cc[7]);
        CEX(cc[0], cc[2]); CEX(cc[1], cc[3]);
        CEX(cc[4], cc[6]); CEX(cc[5], cc[7]);
        CEX(cc[0], cc[1]); CEX(cc[2], cc[3]);
        CEX(cc[4], cc[5]); CEX(cc[6], cc[7]);
#pragma unroll
        for (int j = 0; j < 8; ++j) md[j] = cc[j];
    }

    // parallel exact radius test: lane (Q,k) resolves neighbor k of query Q
    {
        const unsigned ky = md[k];
        int nb;
        if (ky >= SENT) {
            nb = qi;  // unfilled -> self (contributes 0, matches ref)
        } else {
            const int sp = (int)(ky & 0x1FFFu);
            const float4 cc2 = csb[sp];
            const float dx = cc2.x - qx;
            const float dy = cc2.y - qy;
            const float dz = cc2.z - qz;
            const float d2 = fmaf(dx, dx, fmaf(dy, dy, dz * dz));
            // reference: idx = where(sqrt(d2) > 0.1, self_idx, idx)
            nb = (sqrtf(d2) > 0.1f) ? qi : sidx[b * NPTS + sp];
        }
        fidx[Q * KNN + k] = nb;
    }
    __syncthreads();

    // loss gather: 512 threads <-> 64 q x 8 nn, full 16-ch rows
    const int q2 = t >> 3;
    const int j2 = t & 7;
    const int qg = qid[q2];
    const int nb = fidx[q2 * KNN + j2];
    const float* mrow = mask + ((size_t)b * NPTS + qg) * KS;
    const float* nrow = mask + ((size_t)b * NPTS + nb) * KS;
    float acc = 0.0f;
#pragma unroll
    for (int c = 0; c < KS; c += 4) {
        const float4 a = *(const float4*)(mrow + c);
        const float4 v = *(const float4*)(nrow + c);
        acc += fabsf(a.x - v.x) + fabsf(a.y - v.y) +
               fabsf(a.z - v.z) + fabsf(a.w - v.w);
    }

    // block reduction: wave shuffle -> LDS -> one atomic per block
#pragma unroll
    for (int off = 32; off > 0; off >>= 1) acc += __shfl_down(acc, off);
    if ((t & 63) == 0) red[s] = acc;
    __syncthreads();
    if (t == 0) {
        float sum = 0.0f;
#pragma unroll
        for (int i = 0; i < NWAVE; ++i) sum += red[i];
        atomicAdd(out, sum * (1.0f / (BATCH * NPTS * KNN)));
    }
}

extern "C" void kernel_launch(void* const* d_in, const int* in_sizes, int n_in,
                              void* d_out, int out_size, void* d_ws, size_t ws_size,
                              hipStream_t stream) {
    const float* pc   = (const float*)d_in[0];  // (2, 8192, 3)
    const float* mask = (const float*)d_in[1];  // (2, 8192, 16)
    float* out = (float*)d_out;                 // scalar, poisoned 0xAA each call

    // workspace layout (336 KB used)
    float4* cs     = (float4*)d_ws;                              // 256 KB
    int*    sidx   = (int*)((char*)d_ws + 262144);               //  64 KB
    int*    cstart = (int*)((char*)d_ws + 327680);               //   8 KB

    void* args[] = {(void*)&pc, (void*)&mask, (void*)&cs,
                    (void*)&sidx, (void*)&cstart, (void*)&out};
    hipLaunchCooperativeKernel((const void*)fused_kernel,
                               dim3(NBLK), dim3(NTHREADS), args, 0, stream);
}

// Round 13
// 90.767 us; speedup vs baseline: 1.2137x; 1.2137x over previous
//
#include <hip/hip_runtime.h>

// Problem constants (fixed by setup_inputs)
#define BATCH 2
#define NPTS  8192
#define KS    16
#define KNN   8
#define R2LOOSE 0.0101f      // loose prefilter ball; exact radius test at end
#define KEYMASK 0xFFFFE000u  // high 19 bits of d2; low 13 bits = sorted pos
#define NCELL   1000         // 10x10x10 grid, cell size 0.1 (= RADIUS)
#define CSTRIDE 1024         // padded per-batch cell-array stride

// Fused kernel geometry: 256 blocks x 512 threads, 1 block/CU (110KB LDS)
#define QB       64                 // queries per block
#define NWAVE    8                  // waves per block (512 threads)
#define NTHREADS 512
#define CAP      32                 // collect capacity per thread
#define SLAB     256                // per-wave staged candidates per chunk
#define NBLK     (BATCH * NPTS / QB)   // 256 blocks == CU count

// ws is re-poisoned 0xAA each call -> flag deterministically starts at
// 0xAAAAAAAA. 16 builders each +1 -> target. Compared with != (no sign trap).
#define FLAG_BASE   0xAAAAAAAAu
#define FLAG_TARGET (FLAG_BASE + 16u)
#define DONE_LAST   (FLAG_BASE + 255u)

__device__ __forceinline__ int cell_of(float x, float y, float z) {
    int cx = (int)(x * 10.0f); cx = cx > 9 ? 9 : cx;
    int cy = (int)(y * 10.0f); cy = cy > 9 ? 9 : cy;
    int cz = (int)(z * 10.0f); cz = cz > 9 ? 9 : cz;
    return (cx * 10 + cy) * 10 + cz;
}

#define CEX(a, b) { const unsigned mn_ = min(a, b), mx_ = max(a, b); \
                    a = mn_; b = mx_; }

// ---- fused build + knn + loss (R13 = R12 with fence spelling fixed) -------
// R11 post-mortem: cg::grid.sync() + cooperative dispatch cost ~20us (256-way
// arrive/wait + per-block cross-XCD fences). Same fusion, cheap barrier:
// only 16 builders arrive; 240 blocks spin-sleep on one cacheline + one
// acquire fence. Deadlock-safe by capacity: 110KB LDS -> 1 block/CU, grid
// = 256 = CU count -> all co-resident, builders always run.
// R12 failed to compile: __hip_atomic_fence is not a builtin in this ROCm;
// the scoped-fence spelling is __builtin_amdgcn_fence(order, "agent").
__global__ __launch_bounds__(512) void fused_kernel(
    const float* __restrict__ pc,
    const float* __restrict__ mask,
    float4* __restrict__ cs, int* __restrict__ sidx,
    int* __restrict__ cstart, unsigned* __restrict__ flag,
    unsigned* __restrict__ done, float* __restrict__ out)
{
    __shared__ float4   stg4[NWAVE][SLAB];     // 32 KB per-wave slabs
    __shared__ int      stgi[NWAVE][SLAB];     //  8 KB their sorted positions
    __shared__ unsigned sbuf[CAP * NTHREADS];  // 64 KB collect buffer
    __shared__ int      fidx[QB * KNN];        //  2 KB
    __shared__ int      qid[QB];
    __shared__ float    red[NWAVE];
    __shared__ int      h[1024];               //  4 KB build histogram
    __shared__ int      wsum[8];

    const int t = threadIdx.x;
    const int blk = blockIdx.x;
    const int lane = t & 63;
    const int w = t >> 6;

    // ================= Phase A: build (blocks 0..15) =================
    if (blk < 16) {
        const int bb = blk >> 3, seg = blk & 7;   // batch, own segment
        h[t] = 0; h[t + 512] = 0;
        if (blk == 0 && t == 0) out[0] = 0.0f;

        const float* p = pc + (size_t)bb * NPTS * 3;
        float X0[8], Y0[8], Z0[8], X1[8], Y1[8], Z1[8];
        int C0[8], C1[8];
#pragma unroll
        for (int j = 0; j < 8; ++j) {
            const int i0 = j * 1024 + t;
            const int i1 = i0 + 512;
            X0[j] = p[3 * i0]; Y0[j] = p[3 * i0 + 1]; Z0[j] = p[3 * i0 + 2];
            X1[j] = p[3 * i1]; Y1[j] = p[3 * i1 + 1]; Z1[j] = p[3 * i1 + 2];
            C0[j] = cell_of(X0[j], Y0[j], Z0[j]);
            C1[j] = cell_of(X1[j], Y1[j], Z1[j]);
        }
        __syncthreads();   // h zeroed

        int r0 = 0, r1 = 0;
#pragma unroll
        for (int j = 0; j < 8; ++j) {          // segment-ordered rounds
            const int o0 = atomicAdd(&h[C0[j]], 1);
            const int o1 = atomicAdd(&h[C1[j]], 1);
            if (j == seg) { r0 = o0; r1 = o1; }
            __syncthreads();
        }

        // pair-cell exclusive scan: thread t owns cells 2t, 2t+1
        const int c0 = h[2 * t], c1 = h[2 * t + 1];
        const int ps = c0 + c1;
        int inc = ps;
#pragma unroll
        for (int off = 1; off < 64; off <<= 1) {
            const int v = __shfl_up(inc, off);
            if (lane >= off) inc += v;
        }
        if (lane == 63) wsum[w] = inc;
        __syncthreads();
        if (w == 0) {
            const int v = (lane < 8) ? wsum[lane] : 0;
            int iv = v;
#pragma unroll
            for (int off = 1; off < 8; off <<= 1) {
                const int u = __shfl_up(iv, off);
                if (lane >= off) iv += u;
            }
            if (lane < 8) wsum[lane] = iv - v;  // exclusive wave offsets
        }
        __syncthreads();
        const int excl = inc - ps + wsum[w];    // start of cell 2t
        const int s0 = excl, s1 = excl + c0;
        if (seg == 0) {
            cstart[bb * CSTRIDE + 2 * t]     = s0;
            cstart[bb * CSTRIDE + 2 * t + 1] = s1;
        }
        __syncthreads();
        h[2 * t] = s0; h[2 * t + 1] = s1;       // per-cell starts
        __syncthreads();

        // select own-segment points (uniform seg -> cndmask chains)
        float ax = X0[0], ay = Y0[0], az = Z0[0]; int ac = C0[0];
        float bx = X1[0], by = Y1[0], bz = Z1[0]; int bc = C1[0];
#pragma unroll
        for (int j = 1; j < 8; ++j)
            if (seg == j) {
                ax = X0[j]; ay = Y0[j]; az = Z0[j]; ac = C0[j];
                bx = X1[j]; by = Y1[j]; bz = Z1[j]; bc = C1[j];
            }

        const int pos0 = h[ac] + r0;
        const int pos1 = h[bc] + r1;
        const float sqa = fmaf(az, az, fmaf(ay, ay, ax * ax));
        const float sqb = fmaf(bz, bz, fmaf(by, by, bx * bx));
        cs[bb * NPTS + pos0]   = make_float4(ax, ay, az, -0.5f * sqa);
        cs[bb * NPTS + pos1]   = make_float4(bx, by, bz, -0.5f * sqb);
        sidx[bb * NPTS + pos0] = seg * 1024 + t;
        sidx[bb * NPTS + pos1] = seg * 1024 + 512 + t;

        __syncthreads();   // all stores complete before signal
        if (t == 0) {
            __threadfence();   // publish to device scope
            __hip_atomic_fetch_add(flag, 1u, __ATOMIC_RELEASE,
                                   __HIP_MEMORY_SCOPE_AGENT);
        }
    }

    // ---- flag barrier: wait for all 16 builders ----
    if (t == 0) {
        while (__hip_atomic_load(flag, __ATOMIC_RELAXED,
                                 __HIP_MEMORY_SCOPE_AGENT) != FLAG_TARGET)
            __builtin_amdgcn_s_sleep(2);
    }
    __syncthreads();
    __builtin_amdgcn_fence(__ATOMIC_ACQUIRE, "agent");  // invalidate stale L1/L2

    // ================= Phase B: knn + loss (all 256 blocks) =================
    const int l = t & 63;
    const int k = l & 7;          // candidate sublane 0..7
    const int s = t >> 6;         // wave id 0..7
    const int su = __builtin_amdgcn_readfirstlane(s);
    const int Q = (t >> 3) & 63;  // query slot 0..63
    const int b  = blk >> 7;
    const int q0 = (blk & 127) * QB;
    const int qpos = q0 + Q;

    const float4* csb = cs + b * NPTS;
    const float4 qc = csb[qpos];
    const int    qi = sidx[b * NPTS + qpos];
    if (k == 0) qid[Q] = qi;

    const float qx = qc.x, qy = qc.y, qz = qc.z;
    const float qs = -2.0f * qc.w;                 // exact (power of 2)
    const float negthr = (qs - R2LOOSE) * 0.5f;    // pass iff tt >= negthr
    const unsigned SENT = (__float_as_uint(R2LOOSE) & KEYMASK) | 0x1FFFu;

    // wave's 8-query lex-cell run
    int lex = cell_of(qx, qy, qz);
    int cmn = lex, cmx = lex;
#pragma unroll
    for (int off = 32; off; off >>= 1) {
        cmn = min(cmn, __shfl_xor(cmn, off));
        cmx = max(cmx, __shfl_xor(cmx, off));
    }
    const int cfirst = __builtin_amdgcn_readfirstlane(cmn);
    const int clast  = __builtin_amdgcn_readfirstlane(cmx);

    // 9 covering intervals: independent bound loads + value-space dedup
    const int* csp = cstart + b * CSTRIDE;
    const int offs[9] = {-110, -100, -90, -10, 0, 10, 90, 100, 110};
    int praw[9], eraw[9];
#pragma unroll
    for (int i = 0; i < 9; ++i) {
        int lo = cfirst + offs[i] - 1;
        int hp = clast + offs[i] + 2;            // exclusive
        lo = min(max(lo, 0), 1000);
        hp = min(max(hp, 0), 1000);
        praw[i] = csp[lo];
        eraw[i] = csp[hp];
    }
    int P[9], cum[9];
    int runv = 0, Cw = 0;                        // runv == csp[run]
#pragma unroll
    for (int i = 0; i < 9; ++i) {
        const int p = max(praw[i], runv);
        const int e = max(eraw[i], p);
        runv = e;
        P[i] = p; cum[i] = Cw; Cw += e - p;
    }

    // append-only collect, branchless
    int cnt = 0;
    auto EVAL = [&](const float4& c, int spos) {
        const float tt = fmaf(c.x, qx, fmaf(c.y, qy, fmaf(c.z, qz, c.w)));
        const float d2 = fmaxf(fmaf(-2.0f, tt, qs), 0.0f);
        const unsigned key =
            (__float_as_uint(d2) & KEYMASK) | (unsigned)spos;
        const int slot = cnt < (CAP - 1) ? cnt : (CAP - 1);
        sbuf[slot * NTHREADS + t] = key;
        cnt += (tt >= negthr) ? 1 : 0;
    };

    // chunked per-wave stage + eval (wave-local fences only)
    for (int fb = 0; fb < Cw; fb += SLAB) {
        const int n = min(SLAB, Cw - fb);        // wave-uniform
        for (int f = l; f < n; f += 64) {        // 64-wide coalesced stage
            const int g = fb + f;
            int sp = P[0] + g;
#pragma unroll
            for (int i = 1; i < 9; ++i)
                sp = (g >= cum[i]) ? P[i] + (g - cum[i]) : sp;
            stg4[su][f] = csb[sp];
            stgi[su][f] = sp;
        }
        asm volatile("s_waitcnt lgkmcnt(0)" ::: "memory");  // stage visible

        for (int j = k; j < n; j += 8) {         // sublane-strided eval
            const float4 c = stg4[su][j];
            const int   sp = stgi[su][j];
            EVAL(c, sp);
        }
        asm volatile("s_waitcnt lgkmcnt(0)" ::: "memory");  // reads done
    }

    // per-thread ascending top-8 of own collected keys
    unsigned md[KNN];
#pragma unroll
    for (int kk = 0; kk < KNN; ++kk) md[kk] = SENT;
    const int m = cnt < CAP ? cnt : CAP;
    for (int kk = 0; kk < m; ++kk) {
        unsigned ky = sbuf[kk * NTHREADS + t];
#pragma unroll
        for (int i = 0; i < KNN; ++i) {
            const unsigned mn = min(ky, md[i]);
            const unsigned mx = max(ky, md[i]);
            md[i] = mn; ky = mx;
        }
    }

    // in-register bitonic merge across the 8 sublanes of each query group
#pragma unroll
    for (int off = 1; off <= 4; off <<= 1) {
        unsigned bb2[8], cc[8];
#pragma unroll
        for (int j = 0; j < 8; ++j)
            bb2[j] = (unsigned)__shfl_xor((int)md[j], off);
#pragma unroll
        for (int j = 0; j < 8; ++j)
            cc[j] = min(md[j], bb2[7 - j]);
        CEX(cc[0], cc[4]); CEX(cc[1], cc[5]);
        CEX(cc[2], cc[6]); CEX(cc[3], cc[7]);
        CEX(cc[0], cc[2]); CEX(cc[1], cc[3]);
        CEX(cc[4], cc[6]); CEX(cc[5], cc[7]);
        CEX(cc[0], cc[1]); CEX(cc[2], cc[3]);
        CEX(cc[4], cc[5]); CEX(cc[6], cc[7]);
#pragma unroll
        for (int j = 0; j < 8; ++j) md[j] = cc[j];
    }

    // parallel exact radius test: lane (Q,k) resolves neighbor k of query Q
    {
        const unsigned ky = md[k];
        int nb;
        if (ky >= SENT) {
            nb = qi;  // unfilled -> self (contributes 0, matches ref)
        } else {
            const int sp = (int)(ky & 0x1FFFu);
            const float4 cc2 = csb[sp];
            const float dx = cc2.x - qx;
            const float dy = cc2.y - qy;
            const float dz = cc2.z - qz;
            const float d2 = fmaf(dx, dx, fmaf(dy, dy, dz * dz));
            // reference: idx = where(sqrt(d2) > 0.1, self_idx, idx)
            nb = (sqrtf(d2) > 0.1f) ? qi : sidx[b * NPTS + sp];
        }
        fidx[Q * KNN + k] = nb;
    }
    __syncthreads();

    // loss gather: 512 threads <-> 64 q x 8 nn, full 16-ch rows
    const int q2 = t >> 3;
    const int j2 = t & 7;
    const int qg = qid[q2];
    const int nb = fidx[q2 * KNN + j2];
    const float* mrow = mask + ((size_t)b * NPTS + qg) * KS;
    const float* nrow = mask + ((size_t)b * NPTS + nb) * KS;
    float acc = 0.0f;
#pragma unroll
    for (int c = 0; c < KS; c += 4) {
        const float4 a = *(const float4*)(mrow + c);
        const float4 v = *(const float4*)(nrow + c);
        acc += fabsf(a.x - v.x) + fabsf(a.y - v.y) +
               fabsf(a.z - v.z) + fabsf(a.w - v.w);
    }

    // block reduction: wave shuffle -> LDS -> one atomic per block
#pragma unroll
    for (int off = 32; off > 0; off >>= 1) acc += __shfl_down(acc, off);
    if ((t & 63) == 0) red[s] = acc;
    __syncthreads();
    if (t == 0) {
        float sum = 0.0f;
#pragma unroll
        for (int i = 0; i < NWAVE; ++i) sum += red[i];
        atomicAdd(out, sum * (1.0f / (BATCH * NPTS * KNN)));

        // belt & suspenders: last block restores flag/done to the poison
        // value so the protocol also works if ws is ever NOT re-poisoned.
        const unsigned old = __hip_atomic_fetch_add(
            done, 1u, __ATOMIC_ACQ_REL, __HIP_MEMORY_SCOPE_AGENT);
        if (old == DONE_LAST) {
            __hip_atomic_store(flag, FLAG_BASE, __ATOMIC_RELAXED,
                               __HIP_MEMORY_SCOPE_AGENT);
            __hip_atomic_store(done, FLAG_BASE, __ATOMIC_RELAXED,
                               __HIP_MEMORY_SCOPE_AGENT);
        }
    }
}

extern "C" void kernel_launch(void* const* d_in, const int* in_sizes, int n_in,
                              void* d_out, int out_size, void* d_ws, size_t ws_size,
                              hipStream_t stream) {
    const float* pc   = (const float*)d_in[0];  // (2, 8192, 3)
    const float* mask = (const float*)d_in[1];  // (2, 8192, 16)
    float* out = (float*)d_out;                 // scalar, poisoned 0xAA each call

    // workspace layout (336 KB + 2 sync words on separate cachelines)
    float4*   cs     = (float4*)d_ws;                            // 256 KB
    int*      sidx   = (int*)((char*)d_ws + 262144);             //  64 KB
    int*      cstart = (int*)((char*)d_ws + 327680);             //   8 KB
    unsigned* flag   = (unsigned*)((char*)d_ws + 335872);        // poison-init
    unsigned* done   = (unsigned*)((char*)d_ws + 336000);        // poison-init

    hipLaunchKernelGGL(fused_kernel, dim3(NBLK), dim3(NTHREADS), 0, stream,
                       pc, mask, cs, sidx, cstart, flag, done, out);
}

// Round 14
// 70.773 us; speedup vs baseline: 1.5566x; 1.2825x over previous
//
#include <hip/hip_runtime.h>

// Problem constants (fixed by setup_inputs)
#define BATCH 2
#define NPTS  8192
#define KS    16
#define KNN   8
#define R2LOOSE 0.0101f      // loose prefilter ball; exact radius test at end
#define KEYMASK 0xFFFFE000u  // high 19 bits of d2; low 13 bits = sorted pos
#define NCELL   1000         // 10x10x10 grid, cell size 0.1 (= RADIUS)
#define CSTRIDE 1024         // padded per-batch cell-array stride

// Main kernel geometry (R7 best-measured: 8 queries/wave, 8 sublanes)
#define QB       64                 // queries per block
#define NWAVE    8                  // waves per block (512 threads)
#define NTHREADS 512
#define CAP      32                 // collect capacity per thread
#define SLAB     256                // per-wave staged candidates per chunk
#define NBLK     (BATCH * NPTS / QB)   // 256 blocks

__device__ __forceinline__ int cell_of(float x, float y, float z) {
    int cx = (int)(x * 10.0f); cx = cx > 9 ? 9 : cx;
    int cy = (int)(y * 10.0f); cy = cy > 9 ? 9 : cy;
    int cz = (int)(z * 10.0f); cz = cz > 9 ? 9 : cz;
    return (cx * 10 + cy) * 10 + cz;
}

// ---- single build node (R0 version, measured fastest; 6.0us by R6 attrib) --
__global__ __launch_bounds__(1024) void build_kernel(
    const float* __restrict__ pc,
    float4* __restrict__ cs, int* __restrict__ sidx,
    int* __restrict__ cstart, float* __restrict__ out)
{
    __shared__ int h[1024];
    __shared__ int wsum[16];
    const int blk = blockIdx.x, t = threadIdx.x;
    const int b = blk >> 3, seg = blk & 7;     // batch, own segment
    const int lane = t & 63, w = t >> 6;

    h[t] = 0;
    if (blk == 0 && t == 0) out[0] = 0.0f;     // runs before main in-stream

    const float* p = pc + (size_t)b * NPTS * 3;
    float X[8], Y[8], Z[8]; int CC[8];
#pragma unroll
    for (int j = 0; j < 8; ++j) {
        const int i = j * 1024 + t;
        X[j] = p[3 * i]; Y[j] = p[3 * i + 1]; Z[j] = p[3 * i + 2];
        CC[j] = cell_of(X[j], Y[j], Z[j]);
    }
    __syncthreads();   // h zeroed, all loads issued

    int myold = 0;
#pragma unroll
    for (int j = 0; j < 8; ++j) {              // segment-ordered adds
        const int old = atomicAdd(&h[CC[j]], 1);
        if (j == seg) myold = old;             // bel + intra-seg rank
        __syncthreads();
    }

    const int sum = h[t];
    int inc = sum;
#pragma unroll
    for (int off = 1; off < 64; off <<= 1) {
        const int v = __shfl_up(inc, off);
        if (lane >= off) inc += v;
    }
    if (lane == 63) wsum[w] = inc;
    __syncthreads();
    if (w == 0) {
        const int v = (lane < 16) ? wsum[lane] : 0;
        int iv = v;
#pragma unroll
        for (int off = 1; off < 16; off <<= 1) {
            const int u = __shfl_up(iv, off);
            if (lane >= off) iv += u;
        }
        if (lane < 16) wsum[lane] = iv - v;    // exclusive wave offsets
    }
    __syncthreads();
    const int excl = inc - sum + wsum[w];      // per-batch exclusive prefix
    if (seg == 0) cstart[b * CSTRIDE + t] = excl;   // cells>=1000 -> 8192
    __syncthreads();
    h[t] = excl;                               // per-cell start, reusable
    __syncthreads();

    float mx = X[0], my_ = Y[0], mz = Z[0]; int mc = CC[0];
#pragma unroll
    for (int j = 1; j < 8; ++j)
        if (seg == j) { mx = X[j]; my_ = Y[j]; mz = Z[j]; mc = CC[j]; }

    const int pos = h[mc] + myold;
    const float sq = fmaf(mz, mz, fmaf(my_, my_, mx * mx));
    cs[b * NPTS + pos]   = make_float4(mx, my_, mz, -0.5f * sq);
    sidx[b * NPTS + pos] = seg * 1024 + t;     // orig within-batch index
}

// ---- fused knn + loss ------------------------------------------------------
// R14 = R7 (best: 71.8us) with ONE change: the fidx/qid LDS roundtrip and
// its block barrier are deleted. The old epilogue remapped threads as
// (q2,j2) = (t>>3, t&7), which is bit-identical to (Q,k) = ((t>>3)&63, t&7)
// for t<512 -- each thread read back exactly the fidx/qid slot it wrote.
// qi and the resolved neighbor nb are already in this thread's registers,
// so the gather runs inline. knn is now barrier-free until the final
// block reduction. Per-thread acc and reduction order unchanged ->
// bit-identical output.
#define CEX(a, b) { const unsigned mn_ = min(a, b), mx_ = max(a, b); \
                    a = mn_; b = mx_; }

__global__ __launch_bounds__(512) void knn_loss_kernel(
    const float4* __restrict__ cs,     // cell-sorted (x,y,z,-0.5|c|^2)
    const int*    __restrict__ sidx,   // sorted pos -> orig idx
    const int*    __restrict__ cstart, // per-batch cell starts (padded 1024)
    const float*  __restrict__ mask,   // (B, N, KS) in ORIGINAL order
    float* __restrict__ out)
{
    __shared__ float4   stg4[NWAVE][SLAB];     // 32 KB per-wave slabs
    __shared__ int      stgi[NWAVE][SLAB];     //  8 KB their sorted positions
    __shared__ unsigned sbuf[CAP * NTHREADS];  // 64 KB collect buffer
    __shared__ float    red[NWAVE];

    const int t = threadIdx.x;
    const int l = t & 63;
    const int k = l & 7;          // candidate sublane 0..7
    const int s = t >> 6;         // wave id 0..7
    const int su = __builtin_amdgcn_readfirstlane(s);
    const int Q = (t >> 3) & 63;  // query slot 0..63 (= s*8 + qsub)
    const int blk = blockIdx.x;
    const int b  = blk >> 7;
    const int q0 = (blk & 127) * QB;
    const int qpos = q0 + Q;

    const float4* csb = cs + b * NPTS;
    const float4 qc = csb[qpos];
    const int    qi = sidx[b * NPTS + qpos];

    const float qx = qc.x, qy = qc.y, qz = qc.z;
    const float qs = -2.0f * qc.w;                 // exact (power of 2)
    const float negthr = (qs - R2LOOSE) * 0.5f;    // pass iff tt >= negthr
    const unsigned SENT = (__float_as_uint(R2LOOSE) & KEYMASK) | 0x1FFFu;

    // wave's 8-query lex-cell run (8 copies of each query in the wave)
    int lex = cell_of(qx, qy, qz);
    int cmn = lex, cmx = lex;
#pragma unroll
    for (int off = 32; off; off >>= 1) {
        cmn = min(cmn, __shfl_xor(cmn, off));
        cmx = max(cmx, __shfl_xor(cmx, off));
    }
    const int cfirst = __builtin_amdgcn_readfirstlane(cmn);
    const int clast  = __builtin_amdgcn_readfirstlane(cmx);

    // 9 disjoint covering intervals (chained dedup; R7-verified scheme)
    const int* csp = cstart + b * CSTRIDE;
    int P[9], cum[9];
    int run = 0, Cw = 0;
    const int offs[9] = {-110, -100, -90, -10, 0, 10, 90, 100, 110};
#pragma unroll
    for (int i = 0; i < 9; ++i) {
        int lo = cfirst + offs[i] - 1;
        int hp = clast + offs[i] + 2;            // exclusive
        lo = min(max(lo, 0), 1000);
        hp = min(max(hp, 0), 1000);
        lo = max(lo, run);
        hp = max(hp, lo);
        run = hp;
        const int p = csp[lo], e = csp[hp];
        P[i] = p; cum[i] = Cw; Cw += e - p;
    }

    // append-only collect, branchless
    int cnt = 0;
    auto EVAL = [&](const float4& c, int spos) {
        const float tt = fmaf(c.x, qx, fmaf(c.y, qy, fmaf(c.z, qz, c.w)));
        const float d2 = fmaxf(fmaf(-2.0f, tt, qs), 0.0f);
        const unsigned key =
            (__float_as_uint(d2) & KEYMASK) | (unsigned)spos;
        const int slot = cnt < (CAP - 1) ? cnt : (CAP - 1);
        sbuf[slot * NTHREADS + t] = key;
        cnt += (tt >= negthr) ? 1 : 0;
    };

    // chunked per-wave stage + eval (no block barriers; wave-local fence)
    for (int fb = 0; fb < Cw; fb += SLAB) {
        const int n = min(SLAB, Cw - fb);        // wave-uniform
        for (int f = l; f < n; f += 64) {        // 64-wide coalesced stage
            const int g = fb + f;
            int sp = P[0] + g;
#pragma unroll
            for (int i = 1; i < 9; ++i)
                sp = (g >= cum[i]) ? P[i] + (g - cum[i]) : sp;
            stg4[su][f] = csb[sp];
            stgi[su][f] = sp;
        }
        asm volatile("s_waitcnt lgkmcnt(0)" ::: "memory");  // stage visible

        for (int j = k; j < n; j += 8) {         // sublane-strided eval
            const float4 c = stg4[su][j];
            const int   sp = stgi[su][j];
            EVAL(c, sp);
        }
        asm volatile("s_waitcnt lgkmcnt(0)" ::: "memory");  // reads done
    }

    // per-thread ascending top-8 of own collected keys
    unsigned md[KNN];
#pragma unroll
    for (int kk = 0; kk < KNN; ++kk) md[kk] = SENT;
    const int m = cnt < CAP ? cnt : CAP;
    for (int kk = 0; kk < m; ++kk) {
        unsigned ky = sbuf[kk * NTHREADS + t];
#pragma unroll
        for (int i = 0; i < KNN; ++i) {
            const unsigned mn = min(ky, md[i]);
            const unsigned mx = max(ky, md[i]);
            md[i] = mn; ky = mx;
        }
    }

    // in-register bitonic merge across the 8 sublanes of each query group
#pragma unroll
    for (int off = 1; off <= 4; off <<= 1) {
        unsigned bb[8], cc[8];
#pragma unroll
        for (int j = 0; j < 8; ++j)
            bb[j] = (unsigned)__shfl_xor((int)md[j], off);
#pragma unroll
        for (int j = 0; j < 8; ++j)
            cc[j] = min(md[j], bb[7 - j]);
        CEX(cc[0], cc[4]); CEX(cc[1], cc[5]);
        CEX(cc[2], cc[6]); CEX(cc[3], cc[7]);
        CEX(cc[0], cc[2]); CEX(cc[1], cc[3]);
        CEX(cc[4], cc[6]); CEX(cc[5], cc[7]);
        CEX(cc[0], cc[1]); CEX(cc[2], cc[3]);
        CEX(cc[4], cc[5]); CEX(cc[6], cc[7]);
#pragma unroll
        for (int j = 0; j < 8; ++j) md[j] = cc[j];
    }

    // inline epilogue: lane (Q,k) resolves neighbor k of query Q, then
    // gathers its own (query,neighbor) mask-row pair directly (no LDS).
    int nb;
    {
        const unsigned ky = md[k];
        if (ky >= SENT) {
            nb = qi;  // unfilled -> self (contributes 0, matches ref)
        } else {
            const int sp = (int)(ky & 0x1FFFu);
            const float4 cc2 = csb[sp];
            const float dx = cc2.x - qx;
            const float dy = cc2.y - qy;
            const float dz = cc2.z - qz;
            const float d2 = fmaf(dx, dx, fmaf(dy, dy, dz * dz));
            // reference: idx = where(sqrt(d2) > 0.1, self_idx, idx)
            nb = (sqrtf(d2) > 0.1f) ? qi : sidx[b * NPTS + sp];
        }
    }

    // loss gather: thread (Q,k) does its full 16-ch row pair
    const float* mrow = mask + ((size_t)b * NPTS + qi) * KS;
    const float* nrow = mask + ((size_t)b * NPTS + nb) * KS;
    float acc = 0.0f;
#pragma unroll
    for (int c = 0; c < KS; c += 4) {
        const float4 a = *(const float4*)(mrow + c);
        const float4 v = *(const float4*)(nrow + c);
        acc += fabsf(a.x - v.x) + fabsf(a.y - v.y) +
               fabsf(a.z - v.z) + fabsf(a.w - v.w);
    }

    // block reduction: wave shuffle -> LDS -> one atomic per block
#pragma unroll
    for (int off = 32; off > 0; off >>= 1) acc += __shfl_down(acc, off);
    if ((t & 63) == 0) red[s] = acc;
    __syncthreads();
    if (t == 0) {
        float sum = 0.0f;
#pragma unroll
        for (int i = 0; i < NWAVE; ++i) sum += red[i];
        atomicAdd(out, sum * (1.0f / (BATCH * NPTS * KNN)));
    }
}

extern "C" void kernel_launch(void* const* d_in, const int* in_sizes, int n_in,
                              void* d_out, int out_size, void* d_ws, size_t ws_size,
                              hipStream_t stream) {
    const float* pc   = (const float*)d_in[0];  // (2, 8192, 3)
    const float* mask = (const float*)d_in[1];  // (2, 8192, 16)
    float* out = (float*)d_out;                 // scalar, poisoned 0xAA each call

    // workspace layout (336 KB used)
    float4* cs     = (float4*)d_ws;                              // 256 KB
    int*    sidx   = (int*)((char*)d_ws + 262144);               //  64 KB
    int*    cstart = (int*)((char*)d_ws + 327680);               //   8 KB

    hipLaunchKernelGGL(build_kernel, dim3(16), dim3(1024), 0, stream,
                       pc, cs, sidx, cstart, out);
    hipLaunchKernelGGL(knn_loss_kernel, dim3(NBLK), dim3(512), 0, stream,
                       cs, sidx, cstart, mask, out);
}